// Round 2
// baseline (2844.927 us; speedup 1.0000x reference)
//
#include <hip/hip_runtime.h>
#include <stdint.h>

typedef unsigned short ushortT;
typedef float f32x4 __attribute__((ext_vector_type(4)));
typedef short short8 __attribute__((ext_vector_type(8)));

#define HID 3584
#define NH 16
#define NKV 8
#define DH 256
#define SEQ 2048
#define NB 2
#define NTOK 4096
#define INTERDIM 14336
#define ICH 7168  // FFN chunk of INTER
#define WINDOW 1024

__device__ __forceinline__ ushortT f2bf(float x) {
  union { float f; uint32_t u; } v; v.f = x;
  uint32_t r = v.u + 0x7fffu + ((v.u >> 16) & 1u);
  return (ushortT)(r >> 16);
}
__device__ __forceinline__ float bf2f(uint32_t b) {
  union { uint32_t u; float f; } v; v.u = b << 16;
  return v.f;
}
__device__ __forceinline__ void gll16(const void* g, void* l) {
  __builtin_amdgcn_global_load_lds((const __attribute__((address_space(1))) void*)g,
                                   (__attribute__((address_space(3))) void*)l, 16, 0, 0);
}

// ---------------- transpose + fp32->bf16 convert: out[c][r] = in[r][c] ----------------
__global__ __launch_bounds__(256) void transpose_cvt(const float* __restrict__ in,
                                                     ushortT* __restrict__ out,
                                                     int in_rs, int out_rs) {
  __shared__ float tile[64][65];
  const int r0 = blockIdx.y * 64, c0 = blockIdx.x * 64;
  const int t = threadIdx.x, tc = (t & 15) * 4, tr = t >> 4;
#pragma unroll
  for (int p = 0; p < 4; ++p) {
    int r = tr + p * 16;
    float4 v = *(const float4*)&in[(size_t)(r0 + r) * in_rs + c0 + tc];
    tile[r][tc] = v.x; tile[r][tc + 1] = v.y; tile[r][tc + 2] = v.z; tile[r][tc + 3] = v.w;
  }
  __syncthreads();
#pragma unroll
  for (int p = 0; p < 4; ++p) {
    int r = tr + p * 16;
    ushort4 u;
    u.x = f2bf(tile[tc + 0][r]); u.y = f2bf(tile[tc + 1][r]);
    u.z = f2bf(tile[tc + 2][r]); u.w = f2bf(tile[tc + 3][r]);
    *(ushort4*)&out[(size_t)(c0 + r) * out_rs + r0 + tc] = u;
  }
}

// V transpose: vsrc fp32 [(b*S+s)*2048 + n*256 + d] -> vT bf16 [((b*8+n)*256 + d)*2048 + s]
__global__ __launch_bounds__(256) void vtrans(const float* __restrict__ vsrc,
                                              ushortT* __restrict__ vT) {
  __shared__ float tile[64][65];
  const int z = blockIdx.z, b = z >> 3, n = z & 7;
  const float* in = vsrc + (size_t)b * SEQ * (NKV * DH) + n * DH;
  ushortT* out = vT + (size_t)z * DH * SEQ;
  const int s0 = blockIdx.y * 64, d0 = blockIdx.x * 64;
  const int t = threadIdx.x, tc = (t & 15) * 4, tr = t >> 4;
#pragma unroll
  for (int p = 0; p < 4; ++p) {
    int r = tr + p * 16;
    float4 v = *(const float4*)&in[(size_t)(s0 + r) * (NKV * DH) + d0 + tc];
    tile[r][tc] = v.x; tile[r][tc + 1] = v.y; tile[r][tc + 2] = v.z; tile[r][tc + 3] = v.w;
  }
  __syncthreads();
#pragma unroll
  for (int p = 0; p < 4; ++p) {
    int r = tr + p * 16;
    ushort4 u;
    u.x = f2bf(tile[tc + 0][r]); u.y = f2bf(tile[tc + 1][r]);
    u.z = f2bf(tile[tc + 2][r]); u.w = f2bf(tile[tc + 3][r]);
    *(ushort4*)&out[(size_t)(d0 + r) * SEQ + s0 + tc] = u;
  }
}

// ---------------- RMSNorm family (448 threads, 8 cols/thread) ----------------
__device__ __forceinline__ float block_sum448(float v, float* sb) {
#pragma unroll
  for (int o = 32; o; o >>= 1) v += __shfl_xor(v, o, 64);
  __syncthreads();
  if ((threadIdx.x & 63) == 0) sb[threadIdx.x >> 6] = v;
  __syncthreads();
  float s = 0.f;
#pragma unroll
  for (int i = 0; i < 7; ++i) s += sb[i];
  return s;
}

__global__ __launch_bounds__(448) void rms_in(const float* __restrict__ in,
                                              const float* __restrict__ w,
                                              ushortT* __restrict__ out) {
  __shared__ float sb[8];
  const size_t row = blockIdx.x;
  const int c = threadIdx.x * 8;
  const float* p = in + row * HID + c;
  float4 a = *(const float4*)p, bq = *(const float4*)(p + 4);
  float v[8] = {a.x, a.y, a.z, a.w, bq.x, bq.y, bq.z, bq.w};
  float ssq = 0.f;
#pragma unroll
  for (int j = 0; j < 8; ++j) ssq += v[j] * v[j];
  float s = block_sum448(ssq, sb);
  float rs = rsqrtf(s * (1.0f / HID) + 1e-6f);
  uint32_t o[4];
#pragma unroll
  for (int j = 0; j < 4; ++j) {
    float r0 = v[2 * j] * rs * (1.f + w[c + 2 * j]);
    float r1 = v[2 * j + 1] * rs * (1.f + w[c + 2 * j + 1]);
    o[j] = (uint32_t)f2bf(r0) | ((uint32_t)f2bf(r1) << 16);
  }
  *(uint4*)(out + row * HID + c) = make_uint4(o[0], o[1], o[2], o[3]);
}

// NOTE: ao and resid alias (in-place in out_res) -> NO __restrict__ on them.
__global__ __launch_bounds__(448) void rms_add(const float* ao,
                                               const float* __restrict__ h,
                                               const float* __restrict__ w1,
                                               const float* __restrict__ w2,
                                               float* resid,
                                               ushortT* __restrict__ x2) {
  __shared__ float sb[8];
  const size_t row = blockIdx.x;
  const int c = threadIdx.x * 8;
  const float* p = ao + row * HID + c;
  float4 a = *(const float4*)p, bq = *(const float4*)(p + 4);
  float v[8] = {a.x, a.y, a.z, a.w, bq.x, bq.y, bq.z, bq.w};
  float ssq = 0.f;
#pragma unroll
  for (int j = 0; j < 8; ++j) ssq += v[j] * v[j];
  float s1 = block_sum448(ssq, sb);
  float rs1 = rsqrtf(s1 * (1.0f / HID) + 1e-6f);
  const float* hp = h + row * HID + c;
  float4 h0 = *(const float4*)hp, h1 = *(const float4*)(hp + 4);
  float hv[8] = {h0.x, h0.y, h0.z, h0.w, h1.x, h1.y, h1.z, h1.w};
  float r[8];
  float ssq2 = 0.f;
#pragma unroll
  for (int j = 0; j < 8; ++j) {
    r[j] = hv[j] + v[j] * rs1 * (1.f + w1[c + j]);
    ssq2 += r[j] * r[j];
  }
  float* rp = resid + row * HID + c;
  *(float4*)rp = make_float4(r[0], r[1], r[2], r[3]);
  *(float4*)(rp + 4) = make_float4(r[4], r[5], r[6], r[7]);
  float s2 = block_sum448(ssq2, sb);
  float rs2 = rsqrtf(s2 * (1.0f / HID) + 1e-6f);
  uint32_t o[4];
#pragma unroll
  for (int j = 0; j < 4; ++j) {
    float q0 = r[2 * j] * rs2 * (1.f + w2[c + 2 * j]);
    float q1 = r[2 * j + 1] * rs2 * (1.f + w2[c + 2 * j + 1]);
    o[j] = (uint32_t)f2bf(q0) | ((uint32_t)f2bf(q1) << 16);
  }
  *(uint4*)(x2 + row * HID + c) = make_uint4(o[0], o[1], o[2], o[3]);
}

// NOTE: in and out alias (in-place on out_x) -> NO __restrict__.
__global__ __launch_bounds__(448) void rms_out(const float* in,
                                               const float* __restrict__ w,
                                               float* out) {
  __shared__ float sb[8];
  const size_t row = blockIdx.x;
  const int c = threadIdx.x * 8;
  const float* p = in + row * HID + c;
  float4 a = *(const float4*)p, bq = *(const float4*)(p + 4);
  float v[8] = {a.x, a.y, a.z, a.w, bq.x, bq.y, bq.z, bq.w};
  float ssq = 0.f;
#pragma unroll
  for (int j = 0; j < 8; ++j) ssq += v[j] * v[j];
  float s = block_sum448(ssq, sb);
  float rs = rsqrtf(s * (1.0f / HID) + 1e-6f);
  float* op = out + row * HID + c;
  float r[8];
#pragma unroll
  for (int j = 0; j < 8; ++j) r[j] = v[j] * rs * (1.f + w[c + j]);
  *(float4*)op = make_float4(r[0], r[1], r[2], r[3]);
  *(float4*)(op + 4) = make_float4(r[4], r[5], r[6], r[7]);
}

// ---------------- RoPE (bf16 in) ----------------
__global__ __launch_bounds__(128) void rope_q_k(const ushortT* __restrict__ qraw,
                                                const int* __restrict__ pos,
                                                ushortT* __restrict__ qr) {
  const int s = blockIdx.x, h = blockIdx.y, b = blockIdx.z, i = threadIdx.x;
  float p = (float)pos[b * SEQ + s];
  float ang = p * exp2f(-(float)i * (13.287712379549449f / 128.f));
  float sn, cs;
  sincosf(ang, &sn, &cs);
  size_t ib = ((size_t)b * SEQ + s) * (NH * DH) + (size_t)h * DH + i;
  float x1 = bf2f(qraw[ib]), x2 = bf2f(qraw[ib + 128]);
  size_t ob = (((size_t)b * NH + h) * SEQ + s) * DH + i;
  qr[ob] = f2bf(x1 * cs - x2 * sn);
  qr[ob + 128] = f2bf(x2 * cs + x1 * sn);
}

__global__ __launch_bounds__(128) void rope_k_k(const ushortT* __restrict__ kraw,
                                                const int* __restrict__ pos,
                                                ushortT* __restrict__ kr,
                                                float* __restrict__ kv0) {
  const int s = blockIdx.x, n = blockIdx.y, b = blockIdx.z, i = threadIdx.x;
  float p = (float)pos[b * SEQ + s];
  float ang = p * exp2f(-(float)i * (13.287712379549449f / 128.f));
  float sn, cs;
  sincosf(ang, &sn, &cs);
  size_t ib = ((size_t)b * SEQ + s) * (NKV * DH) + (size_t)n * DH + i;
  float x1 = bf2f(kraw[ib]), x2 = bf2f(kraw[ib + 128]);
  float o1 = x1 * cs - x2 * sn, o2 = x2 * cs + x1 * sn;
  size_t ob = (((size_t)b * NKV + n) * SEQ + s) * DH + i;
  kr[ob] = f2bf(o1);
  kr[ob + 128] = f2bf(o2);
  size_t kb = (((size_t)b * SEQ + s) * NKV + n) * DH + i;
  kv0[kb] = o1;
  kv0[kb + 128] = o2;
}

// ---------------- GEMM: C[M][N](op) = A[M][K](bf16,lda) * Bt[N][K](bf16,ldb) ----------------
__device__ __forceinline__ void gemm_stage(const ushortT* gA, const ushortT* gB,
                                           char* lA, char* lB, int lda, int ldb, int tid) {
  const int row_s = tid >> 2;
  const int cb = (tid & 3) * 16;
#pragma unroll
  for (int c = 0; c < 2; ++c) {
    const int row = c * 64 + row_s;
    const int cbs = cb ^ ((row & 3) << 4);
    gll16((const char*)(gA + (size_t)row * lda) + cbs, lA + c * 4096 + tid * 16);
    gll16((const char*)(gB + (size_t)row * ldb) + cbs, lB + c * 4096 + tid * 16);
  }
}

template <int OUTMODE>  // 0 = fp32 store, 1 = bf16 store, 2 = fp32 accumulate
__global__ __launch_bounds__(256) void gemm_bt(const ushortT* __restrict__ A, int lda,
                                               const ushortT* __restrict__ Bt, int ldb,
                                               void* __restrict__ C, int N, int K) {
  __shared__ ushortT As[2][128 * 32];
  __shared__ ushortT Bs[2][128 * 32];
  const int tid = threadIdx.x;
  const int m0 = blockIdx.y * 128, n0 = blockIdx.x * 128;
  const int w = tid >> 6, l = tid & 63, lr = l & 15, lg = l >> 4;
  const int wm = (w >> 1) * 64, wn = (w & 1) * 64;
  f32x4 acc[4][4];
#pragma unroll
  for (int i = 0; i < 4; ++i)
#pragma unroll
    for (int j = 0; j < 4; ++j) acc[i][j] = (f32x4){0.f, 0.f, 0.f, 0.f};

  const int nk = K >> 5;
  const ushortT* Abase = A + (size_t)m0 * lda;
  const ushortT* Bbase = Bt + (size_t)n0 * ldb;
  gemm_stage(Abase, Bbase, (char*)As[0], (char*)Bs[0], lda, ldb, tid);
  for (int kt = 0; kt < nk; ++kt) {
    const int buf = kt & 1;
    __syncthreads();  // drains vmcnt -> buf ready; also fences prior reads of buf^1
    if (kt + 1 < nk)
      gemm_stage(Abase + (size_t)(kt + 1) * 32, Bbase + (size_t)(kt + 1) * 32,
                 (char*)As[buf ^ 1], (char*)Bs[buf ^ 1], lda, ldb, tid);
    short8 af[4], bfr[4];
#pragma unroll
    for (int i = 0; i < 4; ++i) {
      const int ra = wm + i * 16 + lr;
      af[i] = *(const short8*)((const char*)As[buf] + ra * 64 + ((lg * 16) ^ ((ra & 3) << 4)));
      const int rb = wn + i * 16 + lr;
      bfr[i] = *(const short8*)((const char*)Bs[buf] + rb * 64 + ((lg * 16) ^ ((rb & 3) << 4)));
    }
#pragma unroll
    for (int i = 0; i < 4; ++i)
#pragma unroll
      for (int j = 0; j < 4; ++j)
        acc[i][j] = __builtin_amdgcn_mfma_f32_16x16x32_bf16(af[i], bfr[j], acc[i][j], 0, 0, 0);
  }
#pragma unroll
  for (int i = 0; i < 4; ++i)
#pragma unroll
    for (int j = 0; j < 4; ++j)
#pragma unroll
      for (int r = 0; r < 4; ++r) {
        size_t row = (size_t)(m0 + wm + i * 16 + lg * 4 + r);
        size_t col = (size_t)(n0 + wn + j * 16 + lr);
        if (OUTMODE == 0)
          ((float*)C)[row * N + col] = acc[i][j][r];
        else if (OUTMODE == 1)
          ((ushortT*)C)[row * N + col] = f2bf(acc[i][j][r]);
        else
          ((float*)C)[row * N + col] += acc[i][j][r];
      }
}

// ---------------- swiglu: o = up * gelu_tanh(gate), all bf16 ----------------
__global__ __launch_bounds__(256) void swiglu_k(const ushortT* __restrict__ g,
                                                const ushortT* __restrict__ u,
                                                ushortT* __restrict__ o, int n16) {
  int i = blockIdx.x * 256 + threadIdx.x;
  if (i >= n16) return;
  uint4 gv = ((const uint4*)g)[i];
  uint4 uv = ((const uint4*)u)[i];
  uint32_t ga[4] = {gv.x, gv.y, gv.z, gv.w};
  uint32_t ua[4] = {uv.x, uv.y, uv.z, uv.w};
  uint32_t rr[4];
#pragma unroll
  for (int j = 0; j < 4; ++j) {
    float g0 = bf2f(ga[j] & 0xffffu), g1 = bf2f(ga[j] >> 16);
    float u0 = bf2f(ua[j] & 0xffffu), u1 = bf2f(ua[j] >> 16);
    float e0 = 0.5f * g0 * (1.f + tanhf(0.7978845608f * (g0 + 0.044715f * g0 * g0 * g0)));
    float e1 = 0.5f * g1 * (1.f + tanhf(0.7978845608f * (g1 + 0.044715f * g1 * g1 * g1)));
    rr[j] = (uint32_t)f2bf(u0 * e0) | ((uint32_t)f2bf(u1 * e1) << 16);
  }
  ((uint4*)o)[i] = make_uint4(rr[0], rr[1], rr[2], rr[3]);
}

// ---------------- flash attention (sliding window 1024, causal, softcap 50) ----------------
__global__ __launch_bounds__(256) void attn_fwd(const ushortT* __restrict__ Q,   // [B][H][S][DH]
                                                const ushortT* __restrict__ Kk,  // [B][KV][S][DH]
                                                const ushortT* __restrict__ Vt,  // [B][KV][DH][S]
                                                ushortT* __restrict__ Out) {     // [B*S][H*DH]
  __shared__ ushortT Kl[32 * 256];
  __shared__ ushortT Vl[256 * 32];
  __shared__ ushortT Pl[4][16 * 32];
  const int tid = threadIdx.x;
  const int w = tid >> 6, l = tid & 63, lr = l & 15, lg = l >> 4;
  const int h = blockIdx.y, b = blockIdx.z;
  const int n = h >> 1;
  const int qs = blockIdx.x * 64;
  const int sw = qs + w * 16;

  const ushortT* qp = Q + (((size_t)b * NH + h) * SEQ + (sw + lr)) * DH;
  short8 qf[8];
#pragma unroll
  for (int kk = 0; kk < 8; ++kk) qf[kk] = *(const short8*)(qp + kk * 32 + lg * 8);

  f32x4 acc[16];
#pragma unroll
  for (int i = 0; i < 16; ++i) acc[i] = (f32x4){0.f, 0.f, 0.f, 0.f};
  float m_s = -1e30f, l_s = 0.f;

  const ushortT* Kbase = Kk + ((size_t)b * NKV + n) * SEQ * DH;
  const ushortT* Vbase = Vt + ((size_t)b * NKV + n) * DH * SEQ;

  int tlo = qs - (WINDOW - 1);
  if (tlo < 0) tlo = 0;
  const int t0b = tlo & ~31;
  const int nt = (qs + 64 - t0b) >> 5;
  const int scol = sw + lr;  // the s this lane's softmax stats belong to

  for (int it = 0; it < nt; ++it) {
    const int t0 = t0b + it * 32;
    __syncthreads();
    {
      const int rowk = tid >> 5;
      const int cbk = (tid & 31) * 16;
#pragma unroll
      for (int c = 0; c < 4; ++c) {
        int row = c * 8 + rowk;
        int cbs = cbk ^ ((row & 7) << 4);
        gll16((const char*)(Kbase + (size_t)(t0 + row) * DH) + cbs, (char*)Kl + c * 4096 + tid * 16);
      }
      const int rowv = tid >> 2;
      const int cbv = (tid & 3) * 16;
#pragma unroll
      for (int c = 0; c < 4; ++c) {
        int row = c * 64 + rowv;
        int cbs = cbv ^ ((row & 3) << 4);
        gll16((const char*)(Vbase + (size_t)row * SEQ + t0) + cbs, (char*)Vl + c * 4096 + tid * 16);
      }
    }
    __syncthreads();
    // S^T[t][s] = K rows x Q^T  (swapped operands: no P transpose needed later)
    f32x4 st[2];
#pragma unroll
    for (int tt = 0; tt < 2; ++tt) {
      f32x4 a = (f32x4){0.f, 0.f, 0.f, 0.f};
      const int krow = tt * 16 + lr;
      const char* kb = (const char*)Kl + krow * 512;
      const int swz = (krow & 7) << 4;
#pragma unroll
      for (int kk = 0; kk < 8; ++kk) {
        short8 kf = *(const short8*)(kb + ((kk * 64 + lg * 16) ^ swz));
        a = __builtin_amdgcn_mfma_f32_16x16x32_bf16(kf, qf[kk], a, 0, 0, 0);
      }
      st[tt] = a;
    }
    float pvv[8];
    float tmax = -1e30f;
#pragma unroll
    for (int tt = 0; tt < 2; ++tt)
#pragma unroll
      for (int r = 0; r < 4; ++r) {
        int t = t0 + tt * 16 + lg * 4 + r;
        float x = st[tt][r] * 0.0625f;           // SCALING
        x = 50.f * tanhf(x * 0.02f);             // soft cap
        bool ok = (t <= scol) && (scol - t < WINDOW);
        x = ok ? x : -1e30f;
        pvv[tt * 4 + r] = x;
        tmax = fmaxf(tmax, x);
      }
    tmax = fmaxf(tmax, __shfl_xor(tmax, 16, 64));
    tmax = fmaxf(tmax, __shfl_xor(tmax, 32, 64));
    float mnew = fmaxf(m_s, tmax);
    float fsc = __expf(m_s - mnew);
    m_s = mnew;
    float tsum = 0.f;
#pragma unroll
    for (int i = 0; i < 8; ++i) {
      pvv[i] = __expf(pvv[i] - mnew);
      tsum += pvv[i];
    }
    tsum += __shfl_xor(tsum, 16, 64);
    tsum += __shfl_xor(tsum, 32, 64);
    l_s = l_s * fsc + tsum;
    // write P (bf16) to per-wave LDS, swizzled
    {
      char* pb = (char*)&Pl[w][0] + lr * 64;
      const int pswz = (lr & 3) << 4;
#pragma unroll
      for (int tt = 0; tt < 2; ++tt) {
        uint32_t p01 = (uint32_t)f2bf(pvv[tt * 4 + 0]) | ((uint32_t)f2bf(pvv[tt * 4 + 1]) << 16);
        uint32_t p23 = (uint32_t)f2bf(pvv[tt * 4 + 2]) | ((uint32_t)f2bf(pvv[tt * 4 + 3]) << 16);
        *(uint32_t*)(pb + ((tt * 32 + lg * 8 + 0) ^ pswz)) = p01;
        *(uint32_t*)(pb + ((tt * 32 + lg * 8 + 4) ^ pswz)) = p23;
      }
    }
    // rescale accumulator (f per acc-row s = lg*4+r, fetched via shfl)
    float fr[4];
#pragma unroll
    for (int r = 0; r < 4; ++r) fr[r] = __shfl(fsc, lg * 4 + r, 64);
#pragma unroll
    for (int nd = 0; nd < 16; ++nd) {
      acc[nd][0] *= fr[0]; acc[nd][1] *= fr[1];
      acc[nd][2] *= fr[2]; acc[nd][3] *= fr[3];
    }
    // PV: D[s][d] += P(sxT) * V(Txd)
    const char* pfb = (const char*)&Pl[w][0] + lr * 64;
    short8 pf = *(const short8*)(pfb + ((lg * 16) ^ ((lr & 3) << 4)));
#pragma unroll
    for (int nd = 0; nd < 16; ++nd) {
      const int vrow = nd * 16 + lr;
      short8 vf = *(const short8*)((const char*)Vl + vrow * 64 + ((lg * 16) ^ ((vrow & 3) << 4)));
      acc[nd] = __builtin_amdgcn_mfma_f32_16x16x32_bf16(pf, vf, acc[nd], 0, 0, 0);
    }
  }
  float linv[4];
#pragma unroll
  for (int r = 0; r < 4; ++r) linv[r] = 1.f / __shfl(l_s, lg * 4 + r, 64);
#pragma unroll
  for (int nd = 0; nd < 16; ++nd)
#pragma unroll
    for (int r = 0; r < 4; ++r) {
      size_t row = (size_t)b * SEQ + sw + lg * 4 + r;
      Out[row * (NH * DH) + (size_t)h * DH + nd * 16 + lr] = f2bf(acc[nd][r] * linv[r]);
    }
}

// ---------------- host ----------------
// Workspace budget (~238 MiB):
//   W region (102,760,448 B): phase A = qwT(29.4M)+kwT(14.7M)+vwT(14.7M)+owT(29.4M)
//                             phase F = wS0(51.4M)+wS1(51.4M) per FFN chunk
//   R region (146,800,640 B): x:x1/x2(29.4M) | A:qraw_b(33.5M)/attnb | B:kraw_b(16.8M)
//                             | C:qrope(33.5M) | D:krope(16.8M) | E:vT(16.8M)
//                             FFN overlays A..E: gateC(58.7M)+upC(58.7M)
//   attn_out fp32 lives in d_out's out_res region; down-GEMM accumulates into out_x.
extern "C" void kernel_launch(void* const* d_in, const int* in_sizes, int n_in,
                              void* d_out, int out_size, void* d_ws, size_t ws_size,
                              hipStream_t stream) {
  const float* hs = (const float*)d_in[0];
  const int* pos = (const int*)d_in[1];
  const float* w_in = (const float*)d_in[2];
  const float* w_pa = (const float*)d_in[3];
  const float* w_pf = (const float*)d_in[4];
  const float* w_po = (const float*)d_in[5];
  const float* qw = (const float*)d_in[6];
  const float* kw = (const float*)d_in[7];
  const float* vw = (const float*)d_in[8];
  const float* ow = (const float*)d_in[9];
  const float* gw = (const float*)d_in[10];
  const float* uw = (const float*)d_in[11];
  const float* dw = (const float*)d_in[12];

  float* out_x = (float*)d_out;
  float* out_res = out_x + (size_t)NTOK * HID;
  float* out_kv0 = out_res + (size_t)NTOK * HID;
  float* out_kv1 = out_kv0 + (size_t)NTOK * NKV * DH;

  char* ws = (char*)d_ws;
  // W region
  char* W = ws;
  ushortT* qwT = (ushortT*)(W);
  ushortT* kwT = (ushortT*)(W + 29360128);
  ushortT* vwT = (ushortT*)(W + 29360128 + 14680064);
  ushortT* owT = (ushortT*)(W + 29360128 + 2 * 14680064);
  ushortT* wS0 = (ushortT*)(W);              // 51,380,224 B
  ushortT* wS1 = (ushortT*)(W + 51380224);   // 51,380,224 B
  // R region
  char* R = ws + 102760448;
  ushortT* x1 = (ushortT*)(R);                           // 29,360,128
  ushortT* qraw_b = (ushortT*)(R + 29360128);            // 33,554,432 (A)
  ushortT* kraw_b = (ushortT*)(R + 62914560);            // 16,777,216 (B)
  ushortT* qrope = (ushortT*)(R + 79691776);             // 33,554,432 (C)
  ushortT* krope = (ushortT*)(R + 113246208);            // 16,777,216 (D)
  ushortT* vT = (ushortT*)(R + 130023424);               // 16,777,216 (E)
  ushortT* attnb = qraw_b;                               // overlays A after rope_q
  ushortT* x2 = x1;
  ushortT* gateC = (ushortT*)(R + 29360128);             // 58,720,256 (overlays A,B,C-head)
  ushortT* upC = (ushortT*)(R + 29360128 + 58720256);    // 58,720,256 (overlays C-tail,D,E)
  ushortT* interC = gateC;
  float* attn_out = out_res;  // scratch in d_out; becomes residual via in-place rms_add

  // --- phase 1: attention weights -> bf16 transposed ---
  transpose_cvt<<<dim3(4096 / 64, HID / 64), 256, 0, stream>>>(qw, qwT, 4096, HID);
  transpose_cvt<<<dim3(2048 / 64, HID / 64), 256, 0, stream>>>(kw, kwT, 2048, HID);
  transpose_cvt<<<dim3(2048 / 64, HID / 64), 256, 0, stream>>>(vw, vwT, 2048, HID);
  transpose_cvt<<<dim3(HID / 64, 4096 / 64), 256, 0, stream>>>(ow, owT, HID, 4096);

  // --- phase 2: input rmsnorm ---
  rms_in<<<NTOK, 448, 0, stream>>>(hs, w_in, x1);

  // --- phase 3: qkv projections (v -> out_kv1 fp32 directly) ---
  gemm_bt<1><<<dim3(32, 32), 256, 0, stream>>>(x1, HID, qwT, HID, qraw_b, 4096, HID);
  gemm_bt<1><<<dim3(16, 32), 256, 0, stream>>>(x1, HID, kwT, HID, kraw_b, 2048, HID);
  gemm_bt<0><<<dim3(16, 32), 256, 0, stream>>>(x1, HID, vwT, HID, out_kv1, 2048, HID);

  // --- phase 4: rope (+kv_fused k out) + V transpose ---
  rope_q_k<<<dim3(SEQ, NH, NB), 128, 0, stream>>>(qraw_b, pos, qrope);
  rope_k_k<<<dim3(SEQ, NKV, NB), 128, 0, stream>>>(kraw_b, pos, krope, out_kv0);
  vtrans<<<dim3(DH / 64, SEQ / 64, NB * NKV), 256, 0, stream>>>(out_kv1, vT);

  // --- phase 5: attention ---
  attn_fwd<<<dim3(SEQ / 64, NH, NB), 256, 0, stream>>>(qrope, krope, vT, attnb);

  // --- phase 6: output projection (into out_res region) ---
  gemm_bt<0><<<dim3(HID / 128, 32), 256, 0, stream>>>(attnb, 4096, owT, 4096, attn_out, HID, 4096);

  // --- phase 7: post-attn norm + residual (in-place) + pre-ff norm ---
  rms_add<<<NTOK, 448, 0, stream>>>(attn_out, hs, w_pa, w_pf, out_res, x2);

  // --- phases 8-10: FFN in 2 chunks of 7168, down accumulates into out_x ---
  for (int c = 0; c < 2; ++c) {
    transpose_cvt<<<dim3(ICH / 64, HID / 64), 256, 0, stream>>>(gw + (size_t)c * ICH, wS0,
                                                                INTERDIM, HID);
    gemm_bt<1><<<dim3(ICH / 128, 32), 256, 0, stream>>>(x2, HID, wS0, HID, gateC, ICH, HID);
    transpose_cvt<<<dim3(ICH / 64, HID / 64), 256, 0, stream>>>(uw + (size_t)c * ICH, wS1,
                                                                INTERDIM, HID);
    gemm_bt<1><<<dim3(ICH / 128, 32), 256, 0, stream>>>(x2, HID, wS1, HID, upC, ICH, HID);
    int n16 = (int)((size_t)NTOK * ICH / 8);
    swiglu_k<<<(n16 + 255) / 256, 256, 0, stream>>>(gateC, upC, interC, n16);
    transpose_cvt<<<dim3(HID / 64, ICH / 64), 256, 0, stream>>>(dw + (size_t)c * ICH * HID, wS0,
                                                                HID, ICH);
    if (c == 0)
      gemm_bt<0><<<dim3(HID / 128, 32), 256, 0, stream>>>(interC, ICH, wS0, ICH, out_x, HID, ICH);
    else
      gemm_bt<2><<<dim3(HID / 128, 32), 256, 0, stream>>>(interC, ICH, wS0, ICH, out_x, HID, ICH);
  }

  // --- phase 11: final norm (in-place on out_x) ---
  rms_out<<<NTOK, 448, 0, stream>>>(out_x, w_po, out_x);
}

// Round 3
// 2186.590 us; speedup vs baseline: 1.3011x; 1.3011x over previous
//
#include <hip/hip_runtime.h>
#include <stdint.h>

typedef unsigned short ushortT;
typedef float f32x4 __attribute__((ext_vector_type(4)));
typedef short short8 __attribute__((ext_vector_type(8)));

#define HID 3584
#define NH 16
#define NKV 8
#define DH 256
#define SEQ 2048
#define NB 2
#define NTOK 4096
#define INTERDIM 14336
#define ICH 7168  // FFN chunk of INTER
#define WINDOW 1024

__device__ __forceinline__ ushortT f2bf(float x) {
  union { float f; uint32_t u; } v; v.f = x;
  uint32_t r = v.u + 0x7fffu + ((v.u >> 16) & 1u);
  return (ushortT)(r >> 16);
}
__device__ __forceinline__ float bf2f(uint32_t b) {
  union { uint32_t u; float f; } v; v.u = b << 16;
  return v.f;
}
__device__ __forceinline__ void gll16(const void* g, void* l) {
  __builtin_amdgcn_global_load_lds((const __attribute__((address_space(1))) void*)g,
                                   (__attribute__((address_space(3))) void*)l, 16, 0, 0);
}
__device__ __forceinline__ void sbar() {
  asm volatile("" ::: "memory");
  __builtin_amdgcn_s_barrier();
  asm volatile("" ::: "memory");
}
__device__ __forceinline__ void vmdrain() {
  asm volatile("s_waitcnt vmcnt(0)" ::: "memory");
}

// ---------------- transpose + fp32->bf16 convert: out[c][r] = in[r][c] ----------------
__global__ __launch_bounds__(256) void transpose_cvt(const float* __restrict__ in,
                                                     ushortT* __restrict__ out,
                                                     int in_rs, int out_rs) {
  __shared__ float tile[64][65];
  const int r0 = blockIdx.y * 64, c0 = blockIdx.x * 64;
  const int t = threadIdx.x, tc = (t & 15) * 4, tr = t >> 4;
#pragma unroll
  for (int p = 0; p < 4; ++p) {
    int r = tr + p * 16;
    float4 v = *(const float4*)&in[(size_t)(r0 + r) * in_rs + c0 + tc];
    tile[r][tc] = v.x; tile[r][tc + 1] = v.y; tile[r][tc + 2] = v.z; tile[r][tc + 3] = v.w;
  }
  __syncthreads();
#pragma unroll
  for (int p = 0; p < 4; ++p) {
    int r = tr + p * 16;
    ushort4 u;
    u.x = f2bf(tile[tc + 0][r]); u.y = f2bf(tile[tc + 1][r]);
    u.z = f2bf(tile[tc + 2][r]); u.w = f2bf(tile[tc + 3][r]);
    *(ushort4*)&out[(size_t)(c0 + r) * out_rs + r0 + tc] = u;
  }
}

// V transpose: vsrc fp32 [(b*S+s)*2048 + n*256 + d] -> vT bf16 [((b*8+n)*256 + d)*2048 + s]
__global__ __launch_bounds__(256) void vtrans(const float* __restrict__ vsrc,
                                              ushortT* __restrict__ vT) {
  __shared__ float tile[64][65];
  const int z = blockIdx.z, b = z >> 3, n = z & 7;
  const float* in = vsrc + (size_t)b * SEQ * (NKV * DH) + n * DH;
  ushortT* out = vT + (size_t)z * DH * SEQ;
  const int s0 = blockIdx.y * 64, d0 = blockIdx.x * 64;
  const int t = threadIdx.x, tc = (t & 15) * 4, tr = t >> 4;
#pragma unroll
  for (int p = 0; p < 4; ++p) {
    int r = tr + p * 16;
    float4 v = *(const float4*)&in[(size_t)(s0 + r) * (NKV * DH) + d0 + tc];
    tile[r][tc] = v.x; tile[r][tc + 1] = v.y; tile[r][tc + 2] = v.z; tile[r][tc + 3] = v.w;
  }
  __syncthreads();
#pragma unroll
  for (int p = 0; p < 4; ++p) {
    int r = tr + p * 16;
    ushort4 u;
    u.x = f2bf(tile[tc + 0][r]); u.y = f2bf(tile[tc + 1][r]);
    u.z = f2bf(tile[tc + 2][r]); u.w = f2bf(tile[tc + 3][r]);
    *(ushort4*)&out[(size_t)(d0 + r) * SEQ + s0 + tc] = u;
  }
}

// ---------------- RMSNorm family (448 threads, 8 cols/thread) ----------------
__device__ __forceinline__ float block_sum448(float v, float* sb) {
#pragma unroll
  for (int o = 32; o; o >>= 1) v += __shfl_xor(v, o, 64);
  __syncthreads();
  if ((threadIdx.x & 63) == 0) sb[threadIdx.x >> 6] = v;
  __syncthreads();
  float s = 0.f;
#pragma unroll
  for (int i = 0; i < 7; ++i) s += sb[i];
  return s;
}

__global__ __launch_bounds__(448) void rms_in(const float* __restrict__ in,
                                              const float* __restrict__ w,
                                              ushortT* __restrict__ out) {
  __shared__ float sb[8];
  const size_t row = blockIdx.x;
  const int c = threadIdx.x * 8;
  const float* p = in + row * HID + c;
  float4 a = *(const float4*)p, bq = *(const float4*)(p + 4);
  float v[8] = {a.x, a.y, a.z, a.w, bq.x, bq.y, bq.z, bq.w};
  float ssq = 0.f;
#pragma unroll
  for (int j = 0; j < 8; ++j) ssq += v[j] * v[j];
  float s = block_sum448(ssq, sb);
  float rs = rsqrtf(s * (1.0f / HID) + 1e-6f);
  uint32_t o[4];
#pragma unroll
  for (int j = 0; j < 4; ++j) {
    float r0 = v[2 * j] * rs * (1.f + w[c + 2 * j]);
    float r1 = v[2 * j + 1] * rs * (1.f + w[c + 2 * j + 1]);
    o[j] = (uint32_t)f2bf(r0) | ((uint32_t)f2bf(r1) << 16);
  }
  *(uint4*)(out + row * HID + c) = make_uint4(o[0], o[1], o[2], o[3]);
}

// NOTE: ao and resid alias (in-place in out_res) -> NO __restrict__ on them.
__global__ __launch_bounds__(448) void rms_add(const float* ao,
                                               const float* __restrict__ h,
                                               const float* __restrict__ w1,
                                               const float* __restrict__ w2,
                                               float* resid,
                                               ushortT* __restrict__ x2) {
  __shared__ float sb[8];
  const size_t row = blockIdx.x;
  const int c = threadIdx.x * 8;
  const float* p = ao + row * HID + c;
  float4 a = *(const float4*)p, bq = *(const float4*)(p + 4);
  float v[8] = {a.x, a.y, a.z, a.w, bq.x, bq.y, bq.z, bq.w};
  float ssq = 0.f;
#pragma unroll
  for (int j = 0; j < 8; ++j) ssq += v[j] * v[j];
  float s1 = block_sum448(ssq, sb);
  float rs1 = rsqrtf(s1 * (1.0f / HID) + 1e-6f);
  const float* hp = h + row * HID + c;
  float4 h0 = *(const float4*)hp, h1 = *(const float4*)(hp + 4);
  float hv[8] = {h0.x, h0.y, h0.z, h0.w, h1.x, h1.y, h1.z, h1.w};
  float r[8];
  float ssq2 = 0.f;
#pragma unroll
  for (int j = 0; j < 8; ++j) {
    r[j] = hv[j] + v[j] * rs1 * (1.f + w1[c + j]);
    ssq2 += r[j] * r[j];
  }
  float* rp = resid + row * HID + c;
  *(float4*)rp = make_float4(r[0], r[1], r[2], r[3]);
  *(float4*)(rp + 4) = make_float4(r[4], r[5], r[6], r[7]);
  float s2 = block_sum448(ssq2, sb);
  float rs2 = rsqrtf(s2 * (1.0f / HID) + 1e-6f);
  uint32_t o[4];
#pragma unroll
  for (int j = 0; j < 4; ++j) {
    float q0 = r[2 * j] * rs2 * (1.f + w2[c + 2 * j]);
    float q1 = r[2 * j + 1] * rs2 * (1.f + w2[c + 2 * j + 1]);
    o[j] = (uint32_t)f2bf(q0) | ((uint32_t)f2bf(q1) << 16);
  }
  *(uint4*)(x2 + row * HID + c) = make_uint4(o[0], o[1], o[2], o[3]);
}

// NOTE: in and out alias (in-place on out_x) -> NO __restrict__.
__global__ __launch_bounds__(448) void rms_out(const float* in,
                                               const float* __restrict__ w,
                                               float* out) {
  __shared__ float sb[8];
  const size_t row = blockIdx.x;
  const int c = threadIdx.x * 8;
  const float* p = in + row * HID + c;
  float4 a = *(const float4*)p, bq = *(const float4*)(p + 4);
  float v[8] = {a.x, a.y, a.z, a.w, bq.x, bq.y, bq.z, bq.w};
  float ssq = 0.f;
#pragma unroll
  for (int j = 0; j < 8; ++j) ssq += v[j] * v[j];
  float s = block_sum448(ssq, sb);
  float rs = rsqrtf(s * (1.0f / HID) + 1e-6f);
  float* op = out + row * HID + c;
  float r[8];
#pragma unroll
  for (int j = 0; j < 8; ++j) r[j] = v[j] * rs * (1.f + w[c + j]);
  *(float4*)op = make_float4(r[0], r[1], r[2], r[3]);
  *(float4*)(op + 4) = make_float4(r[4], r[5], r[6], r[7]);
}

// ---------------- RoPE (bf16 in) ----------------
__global__ __launch_bounds__(128) void rope_q_k(const ushortT* __restrict__ qraw,
                                                const int* __restrict__ pos,
                                                ushortT* __restrict__ qr) {
  const int s = blockIdx.x, h = blockIdx.y, b = blockIdx.z, i = threadIdx.x;
  float p = (float)pos[b * SEQ + s];
  float ang = p * exp2f(-(float)i * (13.287712379549449f / 128.f));
  float sn, cs;
  sincosf(ang, &sn, &cs);
  size_t ib = ((size_t)b * SEQ + s) * (NH * DH) + (size_t)h * DH + i;
  float x1 = bf2f(qraw[ib]), x2 = bf2f(qraw[ib + 128]);
  size_t ob = (((size_t)b * NH + h) * SEQ + s) * DH + i;
  qr[ob] = f2bf(x1 * cs - x2 * sn);
  qr[ob + 128] = f2bf(x2 * cs + x1 * sn);
}

__global__ __launch_bounds__(128) void rope_k_k(const ushortT* __restrict__ kraw,
                                                const int* __restrict__ pos,
                                                ushortT* __restrict__ kr,
                                                float* __restrict__ kv0) {
  const int s = blockIdx.x, n = blockIdx.y, b = blockIdx.z, i = threadIdx.x;
  float p = (float)pos[b * SEQ + s];
  float ang = p * exp2f(-(float)i * (13.287712379549449f / 128.f));
  float sn, cs;
  sincosf(ang, &sn, &cs);
  size_t ib = ((size_t)b * SEQ + s) * (NKV * DH) + (size_t)n * DH + i;
  float x1 = bf2f(kraw[ib]), x2 = bf2f(kraw[ib + 128]);
  float o1 = x1 * cs - x2 * sn, o2 = x2 * cs + x1 * sn;
  size_t ob = (((size_t)b * NKV + n) * SEQ + s) * DH + i;
  kr[ob] = f2bf(o1);
  kr[ob + 128] = f2bf(o2);
  size_t kb = (((size_t)b * SEQ + s) * NKV + n) * DH + i;
  kv0[kb] = o1;
  kv0[kb + 128] = o2;
}

// ---------------- 256x256 GEMM, BK=64, 8 waves, counted-vmcnt pipeline ----------------
// C[M][N](op) = A[M][K](bf16,lda) * Bt[N][K](bf16,ldb)
// LDS per buffer: A 256x64 (2 halves of 128x64=16KB) + B 256x64; dbuf -> 128 KiB.
// Swizzle: 16B chunk c of row r stored at chunk c^(r&7) (inverse-swz source, swz read).
// Pipeline: stage K-tile t+1 at phases 0-1 of K-tile t (into dead buffer);
//           vmcnt(0)+barrier at phase 0 of each K-tile gates its reads (~3-phase lead).
template <int OUTMODE>  // 0 = fp32 store, 1 = bf16 store, 2 = fp32 accumulate
__global__ __launch_bounds__(512) void gemm256(const ushortT* __restrict__ A, int lda,
                                               const ushortT* __restrict__ Bt, int ldb,
                                               void* __restrict__ C, int N, int K) {
  __shared__ ushortT lds[65536];
  char* lbase = (char*)lds;
  const int tid = threadIdx.x;
  // bijective XCD swizzle (all grids here are multiples of 8)
  const int nwg = gridDim.x * gridDim.y;
  const int lin = blockIdx.y * gridDim.x + blockIdx.x;
  const int cpx = nwg >> 3;
  const int lin2 = (lin & 7) * cpx + (lin >> 3);
  const int bx = lin2 % gridDim.x, by = lin2 / gridDim.x;
  const int m0 = by * 256, n0 = bx * 256;
  const int l = tid & 63, lr = l & 15, lg = l >> 4;
  const int wid = tid >> 6, wm2 = wid >> 2, wn4 = wid & 3;
  const int sr = tid >> 3, sc = tid & 7;  // staging: row 0..63, chunk 0..7

  f32x4 acc[8][4];
#pragma unroll
  for (int i = 0; i < 8; ++i)
#pragma unroll
    for (int j = 0; j < 4; ++j) acc[i][j] = (f32x4){0.f, 0.f, 0.f, 0.f};

  const int nt = K >> 6;
  const ushortT* Abase = A + (size_t)m0 * lda;
  const ushortT* Bbase = Bt + (size_t)n0 * ldb;

  // stage 256 rows x 64 cols (one operand, both halves) into ldst (32KB linear)
  auto stage_op = [&](const ushortT* gsrc, int ld, char* ldst) {
#pragma unroll
    for (int Li = 0; Li < 4; ++Li) {
      int r = Li * 64 + sr;
      gll16((const char*)(gsrc + (size_t)r * ld) + ((sc ^ (r & 7)) << 4),
            ldst + Li * 8192 + tid * 16);
    }
  };

  // prologue: stage K-tile 0 into buf 0
  stage_op(Abase, lda, lbase);
  stage_op(Bbase, ldb, lbase + 32768);

  for (int t = 0; t < nt; ++t) {
    const int cur = t & 1, nxt = cur ^ 1;
    const char* Ab = lbase + cur * 65536 + wm2 * 16384;
    const char* Bb = lbase + cur * 65536 + 32768 + (wn4 >> 1) * 16384;
    short8 af[4][2], bfr[2][2];
#pragma unroll
    for (int q = 0; q < 4; ++q) {
      const int mh = q >> 1, nh = q & 1;
      if (q == 0) vmdrain();  // K-tile t fully staged (issued during t-1)
      sbar();
      // ds-loads for this quadrant
      if (nh == 0) {
#pragma unroll
        for (int i = 0; i < 4; ++i) {
          int rA = mh * 64 + i * 16 + lr;
          int sw = rA & 7;
#pragma unroll
          for (int ks = 0; ks < 2; ++ks)
            af[i][ks] = *(const short8*)(Ab + rA * 128 + (((ks * 4 + lg) ^ sw) << 4));
        }
      }
#pragma unroll
      for (int j = 0; j < 2; ++j) {
        int rB = (wn4 & 1) * 64 + nh * 32 + j * 16 + lr;
        int sw = rB & 7;
#pragma unroll
        for (int ks = 0; ks < 2; ++ks)
          bfr[j][ks] = *(const short8*)(Bb + rB * 128 + (((ks * 4 + lg) ^ sw) << 4));
      }
      // staging issue for K-tile t+1 (dead buffer; safe after this phase's barrier)
      if (q == 0 && t + 1 < nt)
        stage_op(Abase + (size_t)(t + 1) * 64, lda, lbase + nxt * 65536);
      if (q == 1 && t + 1 < nt)
        stage_op(Bbase + (size_t)(t + 1) * 64, ldb, lbase + nxt * 65536 + 32768);
      __builtin_amdgcn_s_setprio(1);
#pragma unroll
      for (int i = 0; i < 4; ++i)
#pragma unroll
        for (int j = 0; j < 2; ++j)
#pragma unroll
          for (int ks = 0; ks < 2; ++ks)
            acc[mh * 4 + i][nh * 2 + j] = __builtin_amdgcn_mfma_f32_16x16x32_bf16(
                af[i][ks], bfr[j][ks], acc[mh * 4 + i][nh * 2 + j], 0, 0, 0);
      __builtin_amdgcn_s_setprio(0);
    }
  }
#pragma unroll
  for (int mi = 0; mi < 8; ++mi)
#pragma unroll
    for (int nj = 0; nj < 4; ++nj)
#pragma unroll
      for (int r = 0; r < 4; ++r) {
        size_t row = (size_t)(m0 + wm2 * 128 + mi * 16 + lg * 4 + r);
        size_t col = (size_t)(n0 + wn4 * 64 + nj * 16 + lr);
        if (OUTMODE == 0)
          ((float*)C)[row * N + col] = acc[mi][nj][r];
        else if (OUTMODE == 1)
          ((ushortT*)C)[row * N + col] = f2bf(acc[mi][nj][r]);
        else
          ((float*)C)[row * N + col] += acc[mi][nj][r];
      }
}

// ---------------- swiglu: o = up * gelu_tanh(gate), all bf16 ----------------
__global__ __launch_bounds__(256) void swiglu_k(const ushortT* __restrict__ g,
                                                const ushortT* __restrict__ u,
                                                ushortT* __restrict__ o, int n16) {
  int i = blockIdx.x * 256 + threadIdx.x;
  if (i >= n16) return;
  uint4 gv = ((const uint4*)g)[i];
  uint4 uv = ((const uint4*)u)[i];
  uint32_t ga[4] = {gv.x, gv.y, gv.z, gv.w};
  uint32_t ua[4] = {uv.x, uv.y, uv.z, uv.w};
  uint32_t rr[4];
#pragma unroll
  for (int j = 0; j < 4; ++j) {
    float g0 = bf2f(ga[j] & 0xffffu), g1 = bf2f(ga[j] >> 16);
    float u0 = bf2f(ua[j] & 0xffffu), u1 = bf2f(ua[j] >> 16);
    float e0 = 0.5f * g0 * (1.f + tanhf(0.7978845608f * (g0 + 0.044715f * g0 * g0 * g0)));
    float e1 = 0.5f * g1 * (1.f + tanhf(0.7978845608f * (g1 + 0.044715f * g1 * g1 * g1)));
    rr[j] = (uint32_t)f2bf(u0 * e0) | ((uint32_t)f2bf(u1 * e1) << 16);
  }
  ((uint4*)o)[i] = make_uint4(rr[0], rr[1], rr[2], rr[3]);
}

// ---------------- flash attention (sliding window 1024, causal, softcap 50) ----------------
__global__ __launch_bounds__(256) void attn_fwd(const ushortT* __restrict__ Q,   // [B][H][S][DH]
                                                const ushortT* __restrict__ Kk,  // [B][KV][S][DH]
                                                const ushortT* __restrict__ Vt,  // [B][KV][DH][S]
                                                ushortT* __restrict__ Out) {     // [B*S][H*DH]
  __shared__ ushortT Kl[32 * 256];
  __shared__ ushortT Vl[256 * 32];
  __shared__ ushortT Pl[4][16 * 32];
  const int tid = threadIdx.x;
  const int w = tid >> 6, l = tid & 63, lr = l & 15, lg = l >> 4;
  const int h = blockIdx.y, b = blockIdx.z;
  const int n = h >> 1;
  const int qs = blockIdx.x * 64;
  const int sw = qs + w * 16;

  const ushortT* qp = Q + (((size_t)b * NH + h) * SEQ + (sw + lr)) * DH;
  short8 qf[8];
#pragma unroll
  for (int kk = 0; kk < 8; ++kk) qf[kk] = *(const short8*)(qp + kk * 32 + lg * 8);

  f32x4 acc[16];
#pragma unroll
  for (int i = 0; i < 16; ++i) acc[i] = (f32x4){0.f, 0.f, 0.f, 0.f};
  float m_s = -1e30f, l_s = 0.f;

  const ushortT* Kbase = Kk + ((size_t)b * NKV + n) * SEQ * DH;
  const ushortT* Vbase = Vt + ((size_t)b * NKV + n) * DH * SEQ;

  int tlo = qs - (WINDOW - 1);
  if (tlo < 0) tlo = 0;
  const int t0b = tlo & ~31;
  const int nt = (qs + 64 - t0b) >> 5;
  const int scol = sw + lr;

  for (int it = 0; it < nt; ++it) {
    const int t0 = t0b + it * 32;
    __syncthreads();
    {
      const int rowk = tid >> 5;
      const int cbk = (tid & 31) * 16;
#pragma unroll
      for (int c = 0; c < 4; ++c) {
        int row = c * 8 + rowk;
        int cbs = cbk ^ ((row & 7) << 4);
        gll16((const char*)(Kbase + (size_t)(t0 + row) * DH) + cbs, (char*)Kl + c * 4096 + tid * 16);
      }
      const int rowv = tid >> 2;
      const int cbv = (tid & 3) * 16;
#pragma unroll
      for (int c = 0; c < 4; ++c) {
        int row = c * 64 + rowv;
        int cbs = cbv ^ ((row & 3) << 4);
        gll16((const char*)(Vbase + (size_t)row * SEQ + t0) + cbs, (char*)Vl + c * 4096 + tid * 16);
      }
    }
    __syncthreads();
    f32x4 st[2];
#pragma unroll
    for (int tt = 0; tt < 2; ++tt) {
      f32x4 a = (f32x4){0.f, 0.f, 0.f, 0.f};
      const int krow = tt * 16 + lr;
      const char* kb = (const char*)Kl + krow * 512;
      const int swz = (krow & 7) << 4;
#pragma unroll
      for (int kk = 0; kk < 8; ++kk) {
        short8 kf = *(const short8*)(kb + ((kk * 64 + lg * 16) ^ swz));
        a = __builtin_amdgcn_mfma_f32_16x16x32_bf16(kf, qf[kk], a, 0, 0, 0);
      }
      st[tt] = a;
    }
    float pvv[8];
    float tmax = -1e30f;
#pragma unroll
    for (int tt = 0; tt < 2; ++tt)
#pragma unroll
      for (int r = 0; r < 4; ++r) {
        int t = t0 + tt * 16 + lg * 4 + r;
        float x = st[tt][r] * 0.0625f;
        x = 50.f * tanhf(x * 0.02f);
        bool ok = (t <= scol) && (scol - t < WINDOW);
        x = ok ? x : -1e30f;
        pvv[tt * 4 + r] = x;
        tmax = fmaxf(tmax, x);
      }
    tmax = fmaxf(tmax, __shfl_xor(tmax, 16, 64));
    tmax = fmaxf(tmax, __shfl_xor(tmax, 32, 64));
    float mnew = fmaxf(m_s, tmax);
    float fsc = __expf(m_s - mnew);
    m_s = mnew;
    float tsum = 0.f;
#pragma unroll
    for (int i = 0; i < 8; ++i) {
      pvv[i] = __expf(pvv[i] - mnew);
      tsum += pvv[i];
    }
    tsum += __shfl_xor(tsum, 16, 64);
    tsum += __shfl_xor(tsum, 32, 64);
    l_s = l_s * fsc + tsum;
    {
      char* pb = (char*)&Pl[w][0] + lr * 64;
      const int pswz = (lr & 3) << 4;
#pragma unroll
      for (int tt = 0; tt < 2; ++tt) {
        uint32_t p01 = (uint32_t)f2bf(pvv[tt * 4 + 0]) | ((uint32_t)f2bf(pvv[tt * 4 + 1]) << 16);
        uint32_t p23 = (uint32_t)f2bf(pvv[tt * 4 + 2]) | ((uint32_t)f2bf(pvv[tt * 4 + 3]) << 16);
        *(uint32_t*)(pb + ((tt * 32 + lg * 8 + 0) ^ pswz)) = p01;
        *(uint32_t*)(pb + ((tt * 32 + lg * 8 + 4) ^ pswz)) = p23;
      }
    }
    float fr[4];
#pragma unroll
    for (int r = 0; r < 4; ++r) fr[r] = __shfl(fsc, lg * 4 + r, 64);
#pragma unroll
    for (int nd = 0; nd < 16; ++nd) {
      acc[nd][0] *= fr[0]; acc[nd][1] *= fr[1];
      acc[nd][2] *= fr[2]; acc[nd][3] *= fr[3];
    }
    const char* pfb = (const char*)&Pl[w][0] + lr * 64;
    short8 pf = *(const short8*)(pfb + ((lg * 16) ^ ((lr & 3) << 4)));
#pragma unroll
    for (int nd = 0; nd < 16; ++nd) {
      const int vrow = nd * 16 + lr;
      short8 vf = *(const short8*)((const char*)Vl + vrow * 64 + ((lg * 16) ^ ((vrow & 3) << 4)));
      acc[nd] = __builtin_amdgcn_mfma_f32_16x16x32_bf16(pf, vf, acc[nd], 0, 0, 0);
    }
  }
  float linv[4];
#pragma unroll
  for (int r = 0; r < 4; ++r) linv[r] = 1.f / __shfl(l_s, lg * 4 + r, 64);
#pragma unroll
  for (int nd = 0; nd < 16; ++nd)
#pragma unroll
    for (int r = 0; r < 4; ++r) {
      size_t row = (size_t)b * SEQ + sw + lg * 4 + r;
      Out[row * (NH * DH) + (size_t)h * DH + nd * 16 + lr] = f2bf(acc[nd][r] * linv[r]);
    }
}

// ---------------- host ----------------
extern "C" void kernel_launch(void* const* d_in, const int* in_sizes, int n_in,
                              void* d_out, int out_size, void* d_ws, size_t ws_size,
                              hipStream_t stream) {
  const float* hs = (const float*)d_in[0];
  const int* pos = (const int*)d_in[1];
  const float* w_in = (const float*)d_in[2];
  const float* w_pa = (const float*)d_in[3];
  const float* w_pf = (const float*)d_in[4];
  const float* w_po = (const float*)d_in[5];
  const float* qw = (const float*)d_in[6];
  const float* kw = (const float*)d_in[7];
  const float* vw = (const float*)d_in[8];
  const float* ow = (const float*)d_in[9];
  const float* gw = (const float*)d_in[10];
  const float* uw = (const float*)d_in[11];
  const float* dw = (const float*)d_in[12];

  float* out_x = (float*)d_out;
  float* out_res = out_x + (size_t)NTOK * HID;
  float* out_kv0 = out_res + (size_t)NTOK * HID;
  float* out_kv1 = out_kv0 + (size_t)NTOK * NKV * DH;

  char* ws = (char*)d_ws;
  // W region
  char* W = ws;
  ushortT* qwT = (ushortT*)(W);
  ushortT* kwT = (ushortT*)(W + 29360128);
  ushortT* vwT = (ushortT*)(W + 29360128 + 14680064);
  ushortT* owT = (ushortT*)(W + 29360128 + 2 * 14680064);
  ushortT* wS0 = (ushortT*)(W);              // 51,380,224 B
  ushortT* wS1 = (ushortT*)(W + 51380224);   // 51,380,224 B
  // R region
  char* R = ws + 102760448;
  ushortT* x1 = (ushortT*)(R);                           // 29,360,128
  ushortT* qraw_b = (ushortT*)(R + 29360128);            // 33,554,432 (A)
  ushortT* kraw_b = (ushortT*)(R + 62914560);            // 16,777,216 (B)
  ushortT* qrope = (ushortT*)(R + 79691776);             // 33,554,432 (C)
  ushortT* krope = (ushortT*)(R + 113246208);            // 16,777,216 (D)
  ushortT* vT = (ushortT*)(R + 130023424);               // 16,777,216 (E)
  ushortT* attnb = qraw_b;
  ushortT* x2 = x1;
  ushortT* gateC = (ushortT*)(R + 29360128);             // 58,720,256
  ushortT* upC = (ushortT*)(R + 29360128 + 58720256);    // 58,720,256
  ushortT* interC = gateC;
  float* attn_out = out_res;

  // --- phase 1: attention weights -> bf16 transposed ---
  transpose_cvt<<<dim3(4096 / 64, HID / 64), 256, 0, stream>>>(qw, qwT, 4096, HID);
  transpose_cvt<<<dim3(2048 / 64, HID / 64), 256, 0, stream>>>(kw, kwT, 2048, HID);
  transpose_cvt<<<dim3(2048 / 64, HID / 64), 256, 0, stream>>>(vw, vwT, 2048, HID);
  transpose_cvt<<<dim3(HID / 64, 4096 / 64), 256, 0, stream>>>(ow, owT, HID, 4096);

  // --- phase 2: input rmsnorm ---
  rms_in<<<NTOK, 448, 0, stream>>>(hs, w_in, x1);

  // --- phase 3: qkv projections (v -> out_kv1 fp32 directly) ---
  gemm256<1><<<dim3(16, 16), 512, 0, stream>>>(x1, HID, qwT, HID, qraw_b, 4096, HID);
  gemm256<1><<<dim3(8, 16), 512, 0, stream>>>(x1, HID, kwT, HID, kraw_b, 2048, HID);
  gemm256<0><<<dim3(8, 16), 512, 0, stream>>>(x1, HID, vwT, HID, out_kv1, 2048, HID);

  // --- phase 4: rope (+kv_fused k out) + V transpose ---
  rope_q_k<<<dim3(SEQ, NH, NB), 128, 0, stream>>>(qraw_b, pos, qrope);
  rope_k_k<<<dim3(SEQ, NKV, NB), 128, 0, stream>>>(kraw_b, pos, krope, out_kv0);
  vtrans<<<dim3(DH / 64, SEQ / 64, NB * NKV), 256, 0, stream>>>(out_kv1, vT);

  // --- phase 5: attention ---
  attn_fwd<<<dim3(SEQ / 64, NH, NB), 256, 0, stream>>>(qrope, krope, vT, attnb);

  // --- phase 6: output projection (into out_res region) ---
  gemm256<0><<<dim3(HID / 256, 16), 512, 0, stream>>>(attnb, 4096, owT, 4096, attn_out, HID, 4096);

  // --- phase 7: post-attn norm + residual (in-place) + pre-ff norm ---
  rms_add<<<NTOK, 448, 0, stream>>>(attn_out, hs, w_pa, w_pf, out_res, x2);

  // --- phases 8-10: FFN in 2 chunks of 7168, down accumulates into out_x ---
  for (int c = 0; c < 2; ++c) {
    transpose_cvt<<<dim3(ICH / 64, HID / 64), 256, 0, stream>>>(gw + (size_t)c * ICH, wS0,
                                                                INTERDIM, HID);
    gemm256<1><<<dim3(ICH / 256, 16), 512, 0, stream>>>(x2, HID, wS0, HID, gateC, ICH, HID);
    transpose_cvt<<<dim3(ICH / 64, HID / 64), 256, 0, stream>>>(uw + (size_t)c * ICH, wS1,
                                                                INTERDIM, HID);
    gemm256<1><<<dim3(ICH / 256, 16), 512, 0, stream>>>(x2, HID, wS1, HID, upC, ICH, HID);
    int n16 = (int)((size_t)NTOK * ICH / 8);
    swiglu_k<<<(n16 + 255) / 256, 256, 0, stream>>>(gateC, upC, interC, n16);
    transpose_cvt<<<dim3(HID / 64, ICH / 64), 256, 0, stream>>>(dw + (size_t)c * ICH * HID, wS0,
                                                                HID, ICH);
    if (c == 0)
      gemm256<0><<<dim3(HID / 256, 16), 512, 0, stream>>>(interC, ICH, wS0, ICH, out_x, HID, ICH);
    else
      gemm256<2><<<dim3(HID / 256, 16), 512, 0, stream>>>(interC, ICH, wS0, ICH, out_x, HID, ICH);
  }

  // --- phase 11: final norm (in-place on out_x) ---
  rms_out<<<NTOK, 448, 0, stream>>>(out_x, w_po, out_x);
}